// Round 16
// baseline (17.761 us; speedup 1.0000x reference)
//
#include <hip/hip_runtime.h>
#include <math.h>

#define NF 8
#define NA 14
#define FT 4      // frames per block (must divide NF)
#define SPLIT 2   // atom-range splits per frame group
#define D_CLAMP 10.0f
#define FAPE_EPS 1e-4f
#define ZINV 0.1f
#define BIAS 1.0f // published slot = true partial + BIAS; unpublished/poison |v|<=0.5

typedef float f2 __attribute__((ext_vector_type(2)));

static __device__ __forceinline__ f2 fma2(f2 a, f2 b, f2 c) {
    return __builtin_elementwise_fma(a, b, c);   // -> v_pk_fma_f32
}

// R13 protocol (single node, zero RMW, block-0 spinner, folded acm) with the
// one untried occupancy config:
//  - SPLIT=2 -> 1536 blocks x (FT=4 frames, half atom range)
//  - __launch_bounds__(256,4): VGPR cap 128 -> 4 blocks/CU = 4 waves/SIMD
//    (+33% TLP vs the 3/SIMD every prior config was pinned at)
//  - SURGICAL forcing: only offn2 (12 VGPRs) forced. Chain-start fma2 needs
//    it (two scalar sources otherwise); chain-middle fmas have their
//    accumulator in VGPR so rp2/rtn2 may stay in SGPRs and still pk-encode.
//    Live set ~100-115 VGPR -> fits the 128 cap without spills (R12's
//    failure was 84 forced VGPRs under an 85 cap).
__global__ __launch_bounds__(256, 4) void fape_one(
    const float* __restrict__ predR,   // (b, N*NF, 3, 3)
    const float* __restrict__ predT,   // (b, N*NF, 3)
    const float* __restrict__ predPos, // (b, N*NA, 3)
    const float* __restrict__ atomMask,// (b, N*NA)
    const float* __restrict__ trueR,
    const float* __restrict__ trueT,
    const float* __restrict__ truePos,
    const float* __restrict__ seqMask, // (b, N)
    float* __restrict__ partial,       // [workBlocks]
    float* __restrict__ out,           // [b]
    int N, int b, int workBlocks)
{
    const int tid = threadIdx.x;
    const int bid = blockIdx.x;
    const int nAtoms    = N * NA;
    const int nFramesPB = N * NF;

    const int fgrp  = bid / SPLIT;
    const int sp    = bid - fgrp * SPLIT;
    const int fg0   = fgrp * FT;
    const int batch = fg0 / nFramesPB;
    const int res   = (fg0 - batch * nFramesPB) / NF;  // uniform over FT frames

    // ---- block-uniform frame constants, packed over frame pairs ----
    f2 rp2[2][9], rtn2[2][9], offn2[2][3];
#pragma unroll
    for (int p = 0; p < 2; ++p) {
#pragma unroll
        for (int h = 0; h < 2; ++h) {
            const int k = 2*p + h;
            const float* Rp = predR + (size_t)(fg0 + k) * 9;
            const float* Rt = trueR + (size_t)(fg0 + k) * 9;
            const float* tp = predT + (size_t)(fg0 + k) * 3;
            const float* tt = trueT + (size_t)(fg0 + k) * 3;
            float rpl[9], rtl[9];
#pragma unroll
            for (int i = 0; i < 9; ++i) { rpl[i] = Rp[i]; rtl[i] = -Rt[i]; }
            const float tp0 = tp[0], tp1 = tp[1], tp2 = tp[2];
            const float tt0 = tt[0], tt1 = tt[1], tt2 = tt[2];
#pragma unroll
            for (int i = 0; i < 9; ++i) { rp2[p][i][h] = rpl[i]; rtn2[p][i][h] = rtl[i]; }
#pragma unroll
            for (int i = 0; i < 3; ++i) {
                offn2[p][i][h] = -(rpl[i]*tp0 + rpl[3+i]*tp1 + rpl[6+i]*tp2)
                                 -(rtl[i]*tt0 + rtl[3+i]*tt1 + rtl[6+i]*tt2);
            }
        }
    }
    // Surgical VGPR forcing: only offn2 (the chain-start's 2nd scalar source).
#pragma unroll
    for (int p = 0; p < 2; ++p)
#pragma unroll
        for (int i = 0; i < 3; ++i) asm volatile("" : "+v"(offn2[p][i]));

    const float* pP  = predPos  + (size_t)batch * nAtoms * 3;
    const float* tP  = truePos  + (size_t)batch * nAtoms * 3;
    const float* aMb = atomMask + (size_t)batch * nAtoms;
    const float* sMb = seqMask  + (size_t)batch * N;
    const float  w   = sMb[res];

    // Contiguous atom half-range for this split (multiples of 4)
    const int aBeg = (nAtoms * sp) / SPLIT;
    const int aEnd = (nAtoms * (sp + 1)) / SPLIT;

    f2 acc2 = {0.0f, 0.0f};
    float acm = 0.0f;                 // folded flat-mask sum over OUR slice
    const f2 eps2 = {FAPE_EPS, FAPE_EPS};
    const f2 cl2  = {D_CLAMP, D_CLAMP};

    auto pairAtom = [&](float pp0, float pp1, float pp2,
                        float pt0, float pt1, float pt2, float m) {
        const f2 vpp0 = {pp0, pp0}, vpp1 = {pp1, pp1}, vpp2 = {pp2, pp2};
        const f2 vpt0 = {pt0, pt0}, vpt1 = {pt1, pt1}, vpt2 = {pt2, pt2};
        const f2 vm   = {m, m};
#pragma unroll
        for (int p = 0; p < 2; ++p) {
            f2 d0 = fma2(rtn2[p][6], vpt2, offn2[p][0]);
            d0 = fma2(rtn2[p][3], vpt1, d0);
            d0 = fma2(rtn2[p][0], vpt0, d0);
            d0 = fma2(rp2[p][6],  vpp2, d0);
            d0 = fma2(rp2[p][3],  vpp1, d0);
            d0 = fma2(rp2[p][0],  vpp0, d0);

            f2 d1 = fma2(rtn2[p][7], vpt2, offn2[p][1]);
            d1 = fma2(rtn2[p][4], vpt1, d1);
            d1 = fma2(rtn2[p][1], vpt0, d1);
            d1 = fma2(rp2[p][7],  vpp2, d1);
            d1 = fma2(rp2[p][4],  vpp1, d1);
            d1 = fma2(rp2[p][1],  vpp0, d1);

            f2 d2 = fma2(rtn2[p][8], vpt2, offn2[p][2]);
            d2 = fma2(rtn2[p][5], vpt1, d2);
            d2 = fma2(rtn2[p][2], vpt0, d2);
            d2 = fma2(rp2[p][8],  vpp2, d2);
            d2 = fma2(rp2[p][5],  vpp1, d2);
            d2 = fma2(rp2[p][2],  vpp0, d2);

            f2 ns = fma2(d2, d2, fma2(d1, d1, fma2(d0, d0, eps2)));
            f2 dist = {__builtin_amdgcn_sqrtf(ns.x), __builtin_amdgcn_sqrtf(ns.y)};
            f2 cl = __builtin_elementwise_min(dist, cl2);   // v_pk_min_f32
            acc2 = fma2(cl, vm, acc2);
        }
    };

    for (int a0 = aBeg + (tid << 2); a0 < aEnd; a0 += 1024) {
        const float4 P0 = *reinterpret_cast<const float4*>(pP + 3*a0);
        const float4 P1 = *reinterpret_cast<const float4*>(pP + 3*a0 + 4);
        const float4 P2 = *reinterpret_cast<const float4*>(pP + 3*a0 + 8);
        const float4 Q0 = *reinterpret_cast<const float4*>(tP + 3*a0);
        const float4 Q1 = *reinterpret_cast<const float4*>(tP + 3*a0 + 4);
        const float4 Q2 = *reinterpret_cast<const float4*>(tP + 3*a0 + 8);
        const float4 AM = *reinterpret_cast<const float4*>(aMb + a0);

        const int q   = a0 / NA;
        const int rem = a0 - q * NA;
        const float s0 = sMb[q];
        const float s1 = sMb[(q + 1 < N) ? (q + 1) : (N - 1)];
        const float m0 = AM.x * s0;
        const float m1 = AM.y * ((rem + 1) >= NA ? s1 : s0);
        const float m2 = AM.z * ((rem + 2) >= NA ? s1 : s0);
        const float m3 = AM.w * ((rem + 3) >= NA ? s1 : s0);

        acm += (m0 + m1) + (m2 + m3);   // free atom_count byproduct (our slice)

        pairAtom(P0.x, P0.y, P0.z,  Q0.x, Q0.y, Q0.z,  m0);
        pairAtom(P0.w, P1.x, P1.y,  Q0.w, Q1.x, Q1.y,  m1);
        pairAtom(P1.z, P1.w, P2.x,  Q1.z, Q1.w, Q2.x,  m2);
        pairAtom(P2.y, P2.z, P2.w,  Q2.y, Q2.z, Q2.w,  m3);
    }

    float acc = acc2.x + acc2.y;
#pragma unroll
    for (int o = 32; o > 0; o >>= 1) acc += __shfl_down(acc, o, 64);

    __shared__ float sRed[4];
    if ((tid & 63) == 0) sRed[tid >> 6] = acc;
    __syncthreads();
    if (tid == 0) {
        const float v = (sRed[0] + sRed[1] + sRed[2] + sRed[3]) * w + BIAS;
        __hip_atomic_store(&partial[bid], v, __ATOMIC_RELAXED,
                           __HIP_MEMORY_SCOPE_AGENT);
    }

    if (bid != 0) return;

    // ================== block 0: reducer ==================
    const int spb = workBlocks / b;   // slots per batch, contiguous
    __shared__ float wsS[4], wsA[4], wsF[4];

    for (int B = 0; B < b; ++B) {
        float ac, fc = 0.0f;
        const float* sMB = seqMask + (size_t)B * N;
        for (int n = tid; n < N; n += 256) fc += sMB[n];

        if (B == 0) {
            // our main loop folded atoms [0, nAtoms/2); add the complement
            ac = acm;
            const float* aMB = atomMask;
            for (int a0 = (nAtoms / SPLIT) + (tid << 2); a0 < nAtoms; a0 += 1024) {
                const float4 AM = *reinterpret_cast<const float4*>(aMB + a0);
                const int q   = a0 / NA;
                const int rem = a0 - q * NA;
                ac += AM.x * sMB[q]
                    + AM.y * sMB[q + ((rem + 1) >= NA ? 1 : 0)]
                    + AM.z * sMB[q + ((rem + 2) >= NA ? 1 : 0)]
                    + AM.w * sMB[q + ((rem + 3) >= NA ? 1 : 0)];
            }
        } else {
            const float* aMB = atomMask + (size_t)B * nAtoms;
            ac = 0.0f;
            for (int a0 = (tid << 2); a0 < nAtoms; a0 += 1024) {
                const float4 AM = *reinterpret_cast<const float4*>(aMB + a0);
                const int q   = a0 / NA;
                const int rem = a0 - q * NA;
                ac += AM.x * sMB[q]
                    + AM.y * sMB[q + ((rem + 1) >= NA ? 1 : 0)]
                    + AM.z * sMB[q + ((rem + 2) >= NA ? 1 : 0)]
                    + AM.w * sMB[q + ((rem + 3) >= NA ? 1 : 0)];
            }
        }

        // Spin-read this batch's slots (lone spinner; real slots >= BIAS)
        const float* slots = partial + (size_t)B * spb;
        float s = 0.0f;
        for (int i = tid; i < spb; i += 256) {
            float v = __hip_atomic_load(&slots[i], __ATOMIC_RELAXED,
                                        __HIP_MEMORY_SCOPE_AGENT);
            while (fabsf(v) <= 0.5f) {
                __builtin_amdgcn_s_sleep(1);
                v = __hip_atomic_load(&slots[i], __ATOMIC_RELAXED,
                                      __HIP_MEMORY_SCOPE_AGENT);
            }
            s += v - BIAS;
        }

#pragma unroll
        for (int o = 32; o > 0; o >>= 1) {
            s  += __shfl_down(s,  o, 64);
            ac += __shfl_down(ac, o, 64);
            fc += __shfl_down(fc, o, 64);
        }
        __syncthreads();   // ws reuse across batch iterations
        if ((tid & 63) == 0) {
            wsS[tid >> 6] = s; wsA[tid >> 6] = ac; wsF[tid >> 6] = fc;
        }
        __syncthreads();
        if (tid == 0) {
            const float S  = wsS[0] + wsS[1] + wsS[2] + wsS[3];
            const float AC = fmaxf(wsA[0] + wsA[1] + wsA[2] + wsA[3], 1.0f);
            const float FC = fmaxf((wsF[0] + wsF[1] + wsF[2] + wsF[3]) * (float)NF, 1.0f);
            out[B] = S / AC / FC * ZINV;
        }
    }
}

extern "C" void kernel_launch(void* const* d_in, const int* in_sizes, int n_in,
                              void* d_out, int out_size, void* d_ws, size_t ws_size,
                              hipStream_t stream) {
    const float* predR   = (const float*)d_in[0];
    const float* predT   = (const float*)d_in[1];
    const float* predPos = (const float*)d_in[2];
    const float* atomM   = (const float*)d_in[3];
    const float* trueR   = (const float*)d_in[4];
    const float* trueT   = (const float*)d_in[5];
    const float* truePos = (const float*)d_in[6];
    const float* seqM    = (const float*)d_in[7];
    float* out = (float*)d_out;

    const int b = out_size;                   // fape_loss has shape (b,)
    const int N = in_sizes[7] / b;            // seq_mask is (b, N)
    const int totalFrames = b * N * NF;
    const int workBlocks  = (totalFrames / FT) * SPLIT;  // 1536 for N=384

    float* partial = (float*)d_ws;            // workBlocks floats

    fape_one<<<workBlocks, 256, 0, stream>>>(
        predR, predT, predPos, atomM, trueR, trueT, truePos, seqM,
        partial, out, N, b, workBlocks);
}

// Round 17
// 16.520 us; speedup vs baseline: 1.0752x; 1.0752x over previous
//
#include <hip/hip_runtime.h>
#include <math.h>

#define NF 8
#define NA 14
#define FT 4      // frames per block (must divide NF)
#define D_CLAMP 10.0f
#define FAPE_EPS 1e-4f
#define ZINV 0.1f
#define BIAS 1.0f // published slot = true partial + BIAS; unpublished/poison |v|<=0.5

typedef float f2 __attribute__((ext_vector_type(2)));

static __device__ __forceinline__ f2 fma2(f2 a, f2 b, f2 c) {
    return __builtin_elementwise_fma(a, b, c);   // -> v_pk_fma_f32 (all-VGPR srcs)
}

// FINAL champion (R13, 16.63us; reproduced R15 at 16.80us):
// single node, 768 blocks, (256,3), zero RMW atomics, block-0 spinner,
// folded acm, all frame constants forced to VGPR (VOP3P pk-encodable),
// 2-scalar seq-mask loads per iteration. All structural alternatives probed
// and slower; remaining time = ~6.3us graph overhead + latency-bound work
// loop at the compiler's optimal schedule + ~1us tail.
__global__ __launch_bounds__(256, 3) void fape_one(
    const float* __restrict__ predR,   // (b, N*NF, 3, 3)
    const float* __restrict__ predT,   // (b, N*NF, 3)
    const float* __restrict__ predPos, // (b, N*NA, 3)
    const float* __restrict__ atomMask,// (b, N*NA)
    const float* __restrict__ trueR,
    const float* __restrict__ trueT,
    const float* __restrict__ truePos,
    const float* __restrict__ seqMask, // (b, N)
    float* __restrict__ partial,       // [workBlocks]
    float* __restrict__ out,           // [b]
    int N, int b, int workBlocks)
{
    const int tid = threadIdx.x;
    const int bid = blockIdx.x;
    const int nAtoms    = N * NA;
    const int nFramesPB = N * NF;
    const int fg0   = bid * FT;
    const int batch = fg0 / nFramesPB;
    const int res   = (fg0 - batch * nFramesPB) / NF;  // uniform over FT frames

    // ---- block-uniform frame constants, packed over frame pairs ----
    f2 rp2[2][9], rtn2[2][9], offn2[2][3];
#pragma unroll
    for (int p = 0; p < 2; ++p) {
#pragma unroll
        for (int h = 0; h < 2; ++h) {
            const int k = 2*p + h;
            const float* Rp = predR + (size_t)(fg0 + k) * 9;
            const float* Rt = trueR + (size_t)(fg0 + k) * 9;
            const float* tp = predT + (size_t)(fg0 + k) * 3;
            const float* tt = trueT + (size_t)(fg0 + k) * 3;
            float rpl[9], rtl[9];
#pragma unroll
            for (int i = 0; i < 9; ++i) { rpl[i] = Rp[i]; rtl[i] = -Rt[i]; }
            const float tp0 = tp[0], tp1 = tp[1], tp2 = tp[2];
            const float tt0 = tt[0], tt1 = tt[1], tt2 = tt[2];
#pragma unroll
            for (int i = 0; i < 9; ++i) { rp2[p][i][h] = rpl[i]; rtn2[p][i][h] = rtl[i]; }
#pragma unroll
            for (int i = 0; i < 3; ++i) {
                offn2[p][i][h] = -(rpl[i]*tp0 + rpl[3+i]*tp1 + rpl[6+i]*tp2)
                                 -(rtl[i]*tt0 + rtl[3+i]*tt1 + rtl[6+i]*tt2);
            }
        }
    }

    // Force all frame constants into VGPRs so VOP3P pk ops are encodable
    // (VOP3P: max one scalar source; two SGPR constants per fma would
    // otherwise scalarize the whole chain).
#pragma unroll
    for (int p = 0; p < 2; ++p) {
#pragma unroll
        for (int i = 0; i < 9; ++i) {
            asm volatile("" : "+v"(rp2[p][i]));
            asm volatile("" : "+v"(rtn2[p][i]));
        }
#pragma unroll
        for (int i = 0; i < 3; ++i) asm volatile("" : "+v"(offn2[p][i]));
    }

    const float* pP  = predPos  + (size_t)batch * nAtoms * 3;
    const float* tP  = truePos  + (size_t)batch * nAtoms * 3;
    const float* aMb = atomMask + (size_t)batch * nAtoms;
    const float* sMb = seqMask  + (size_t)batch * N;
    const float  w   = sMb[res];

    f2 acc2 = {0.0f, 0.0f};
    float acm = 0.0f;                 // folded atom_count (flat-mask sum)
    const f2 eps2 = {FAPE_EPS, FAPE_EPS};
    const f2 cl2  = {D_CLAMP, D_CLAMP};

    auto pairAtom = [&](float pp0, float pp1, float pp2,
                        float pt0, float pt1, float pt2, float m) {
        const f2 vpp0 = {pp0, pp0}, vpp1 = {pp1, pp1}, vpp2 = {pp2, pp2};
        const f2 vpt0 = {pt0, pt0}, vpt1 = {pt1, pt1}, vpt2 = {pt2, pt2};
        const f2 vm   = {m, m};
#pragma unroll
        for (int p = 0; p < 2; ++p) {
            f2 d0 = fma2(rtn2[p][6], vpt2, offn2[p][0]);
            d0 = fma2(rtn2[p][3], vpt1, d0);
            d0 = fma2(rtn2[p][0], vpt0, d0);
            d0 = fma2(rp2[p][6],  vpp2, d0);
            d0 = fma2(rp2[p][3],  vpp1, d0);
            d0 = fma2(rp2[p][0],  vpp0, d0);

            f2 d1 = fma2(rtn2[p][7], vpt2, offn2[p][1]);
            d1 = fma2(rtn2[p][4], vpt1, d1);
            d1 = fma2(rtn2[p][1], vpt0, d1);
            d1 = fma2(rp2[p][7],  vpp2, d1);
            d1 = fma2(rp2[p][4],  vpp1, d1);
            d1 = fma2(rp2[p][1],  vpp0, d1);

            f2 d2 = fma2(rtn2[p][8], vpt2, offn2[p][2]);
            d2 = fma2(rtn2[p][5], vpt1, d2);
            d2 = fma2(rtn2[p][2], vpt0, d2);
            d2 = fma2(rp2[p][8],  vpp2, d2);
            d2 = fma2(rp2[p][5],  vpp1, d2);
            d2 = fma2(rp2[p][2],  vpp0, d2);

            f2 ns = fma2(d2, d2, fma2(d1, d1, fma2(d0, d0, eps2)));
            f2 dist = {__builtin_amdgcn_sqrtf(ns.x), __builtin_amdgcn_sqrtf(ns.y)};
            f2 cl = __builtin_elementwise_min(dist, cl2);   // v_pk_min_f32
            acc2 = fma2(cl, vm, acc2);
        }
    };

    for (int a0 = tid << 2; a0 < nAtoms; a0 += 1024) {
        const float4 P0 = *reinterpret_cast<const float4*>(pP + 3*a0);
        const float4 P1 = *reinterpret_cast<const float4*>(pP + 3*a0 + 4);
        const float4 P2 = *reinterpret_cast<const float4*>(pP + 3*a0 + 8);
        const float4 Q0 = *reinterpret_cast<const float4*>(tP + 3*a0);
        const float4 Q1 = *reinterpret_cast<const float4*>(tP + 3*a0 + 4);
        const float4 Q2 = *reinterpret_cast<const float4*>(tP + 3*a0 + 8);
        const float4 AM = *reinterpret_cast<const float4*>(aMb + a0);

        const int q   = a0 / NA;
        const int rem = a0 - q * NA;
        // Two register-resident seq-mask values instead of 4 gathers.
        const float s0 = sMb[q];
        const float s1 = sMb[(q + 1 < N) ? (q + 1) : (N - 1)];
        const float m0 = AM.x * s0;
        const float m1 = AM.y * ((rem + 1) >= NA ? s1 : s0);
        const float m2 = AM.z * ((rem + 2) >= NA ? s1 : s0);
        const float m3 = AM.w * ((rem + 3) >= NA ? s1 : s0);

        acm += (m0 + m1) + (m2 + m3);   // free atom_count byproduct

        pairAtom(P0.x, P0.y, P0.z,  Q0.x, Q0.y, Q0.z,  m0);
        pairAtom(P0.w, P1.x, P1.y,  Q0.w, Q1.x, Q1.y,  m1);
        pairAtom(P1.z, P1.w, P2.x,  Q1.z, Q1.w, Q2.x,  m2);
        pairAtom(P2.y, P2.z, P2.w,  Q2.y, Q2.z, Q2.w,  m3);
    }

    float acc = acc2.x + acc2.y;
#pragma unroll
    for (int o = 32; o > 0; o >>= 1) acc += __shfl_down(acc, o, 64);

    __shared__ float sRed[4];
    if ((tid & 63) == 0) sRed[tid >> 6] = acc;
    __syncthreads();
    if (tid == 0) {
        const float v = (sRed[0] + sRed[1] + sRed[2] + sRed[3]) * w + BIAS;
        __hip_atomic_store(&partial[bid], v, __ATOMIC_RELAXED,
                           __HIP_MEMORY_SCOPE_AGENT);
    }

    if (bid != 0) return;

    // ================== block 0: reducer ==================
    const int spb = workBlocks / b;   // slots per batch, contiguous
    __shared__ float wsS[4], wsA[4], wsF[4];

    for (int B = 0; B < b; ++B) {
        float ac, fc = 0.0f;
        const float* sMB = seqMask + (size_t)B * N;
        for (int n = tid; n < N; n += 256) fc += sMB[n];

        if (B == 0) {
            ac = acm;                 // folded during the work loop
        } else {
            const float* aMB = atomMask + (size_t)B * nAtoms;
            ac = 0.0f;
            for (int a0 = (tid << 2); a0 < nAtoms; a0 += 1024) {
                const float4 AM = *reinterpret_cast<const float4*>(aMB + a0);
                const int q   = a0 / NA;
                const int rem = a0 - q * NA;
                ac += AM.x * sMB[q]
                    + AM.y * sMB[q + ((rem + 1) >= NA ? 1 : 0)]
                    + AM.z * sMB[q + ((rem + 2) >= NA ? 1 : 0)]
                    + AM.w * sMB[q + ((rem + 3) >= NA ? 1 : 0)];
            }
        }

        // Spin-read this batch's slots (lone spinner; real slots >= BIAS)
        const float* slots = partial + (size_t)B * spb;
        float s = 0.0f;
        for (int i = tid; i < spb; i += 256) {
            float v = __hip_atomic_load(&slots[i], __ATOMIC_RELAXED,
                                        __HIP_MEMORY_SCOPE_AGENT);
            while (fabsf(v) <= 0.5f) {
                __builtin_amdgcn_s_sleep(1);
                v = __hip_atomic_load(&slots[i], __ATOMIC_RELAXED,
                                      __HIP_MEMORY_SCOPE_AGENT);
            }
            s += v - BIAS;
        }

#pragma unroll
        for (int o = 32; o > 0; o >>= 1) {
            s  += __shfl_down(s,  o, 64);
            ac += __shfl_down(ac, o, 64);
            fc += __shfl_down(fc, o, 64);
        }
        __syncthreads();   // ws reuse across batch iterations
        if ((tid & 63) == 0) {
            wsS[tid >> 6] = s; wsA[tid >> 6] = ac; wsF[tid >> 6] = fc;
        }
        __syncthreads();
        if (tid == 0) {
            const float S  = wsS[0] + wsS[1] + wsS[2] + wsS[3];
            const float AC = fmaxf(wsA[0] + wsA[1] + wsA[2] + wsA[3], 1.0f);
            const float FC = fmaxf((wsF[0] + wsF[1] + wsF[2] + wsF[3]) * (float)NF, 1.0f);
            out[B] = S / AC / FC * ZINV;
        }
    }
}

extern "C" void kernel_launch(void* const* d_in, const int* in_sizes, int n_in,
                              void* d_out, int out_size, void* d_ws, size_t ws_size,
                              hipStream_t stream) {
    const float* predR   = (const float*)d_in[0];
    const float* predT   = (const float*)d_in[1];
    const float* predPos = (const float*)d_in[2];
    const float* atomM   = (const float*)d_in[3];
    const float* trueR   = (const float*)d_in[4];
    const float* trueT   = (const float*)d_in[5];
    const float* truePos = (const float*)d_in[6];
    const float* seqM    = (const float*)d_in[7];
    float* out = (float*)d_out;

    const int b = out_size;                   // fape_loss has shape (b,)
    const int N = in_sizes[7] / b;            // seq_mask is (b, N)
    const int totalFrames = b * N * NF;
    const int workBlocks  = totalFrames / FT; // 768 for N=384 -> single tranche

    float* partial = (float*)d_ws;            // workBlocks floats

    fape_one<<<workBlocks, 256, 0, stream>>>(
        predR, predT, predPos, atomM, trueR, trueT, truePos, seqM,
        partial, out, N, b, workBlocks);
}